// Round 3
// baseline (163.759 us; speedup 1.0000x reference)
//
#include <hip/hip_runtime.h>

// Cost volume: B=4, C=32, H=256, W=256, D=9, G=8, cpg=4
// out[b,g,d,h,w] = mean_{c in group g} var(warp_l, warp_r, feat_ref)
//
// R4: row-blocked pipeline. R1/R2/R3 (wildly different VALU/LDS structure)
// all pinned at 55.5us with identical FETCH/WRITE => memory-system
// service-rate bound, waves 93% stalled. Attack the service rate:
//  - 1 block = 4 consecutive rows of one (b,g): contiguous 4KB reads per
//    input plane (vs 1KB slivers), 4 consecutive row writes per output
//    plane, grid 2048 = exactly 8 blocks/CU.
//  - Double-buffered LDS staging (2 x 8.3KB), prefetch row r+1 into regs
//    while computing row r (issue-early / write-late), so every CU always
//    has a load burst in flight behind the compute.
//  - Math unchanged from R3 (3-tap hat weights + Q - S^2/3 variance).

#define B_ 4
#define C_ 32
#define H_ 256
#define W_ 256
#define D_ 9
#define G_ 8
#define CPG 4
#define HW_ (H_ * W_)
#define SW_ 260   // staged row: x in [-2, W+1]
#define ROWS 4

typedef float v2f __attribute__((ext_vector_type(2)));

static __device__ __forceinline__ v2f sp(float x) {
    v2f r; r.x = x; r.y = x; return r;
}

__global__ __launch_bounds__(256) void cost_volume_kernel(
    const float* __restrict__ fref,
    const float* __restrict__ fls,
    const float* __restrict__ frs,
    const float* __restrict__ disp0,
    float* __restrict__ out)
{
    const float kRes[D_] = {-0.4f, -0.3f, -0.2f, -0.1f, 0.0f,
                             0.1f,  0.2f,  0.3f,  0.4f};

    __shared__ float sL[2][CPG][SW_];
    __shared__ float sR[2][CPG][SW_];

    const int bid = blockIdx.x;
    const int g  = bid & (G_ - 1);
    const int t  = bid >> 3;
    const int h0 = (t & (H_ / ROWS - 1)) * ROWS;
    const int b  = t >> 6;
    const int w  = threadIdx.x;

    // disp for all 4 rows, issued up front (independent of everything)
    const unsigned dbbase = (unsigned)((b * H_ + h0) * W_ + w);
    float dsp[ROWS];
    #pragma unroll
    for (int r = 0; r < ROWS; ++r) dsp[r] = disp0[dbbase + (unsigned)(r * W_)];

    const unsigned rowbase0 = (unsigned)(((b * C_ + g * CPG) * HW_) + h0 * W_);

    // ---- register-staged row load (issue-early) ----
    float rL[CPG], rR[CPG], rF[CPG], hx = 0.0f;
    const bool vmain = (w >= 2);
    const int  xmain = w - 2;                 // LDS slot w holds x = w-2
    // halo: threads 0..31 each fetch one of 8 (side,ch) x 4 slots 256..259
    const int hcs = w >> 2, hk = w & 3;
    const int hx2 = 254 + hk;
    const bool hval = (w < 32) && (hx2 < W_);

    auto LOADROW = [&](int r) {
        const float* __restrict__ ls = fls  + rowbase0 + (unsigned)(r * W_);
        const float* __restrict__ rs = frs  + rowbase0 + (unsigned)(r * W_);
        const float* __restrict__ rf = fref + rowbase0 + (unsigned)(r * W_);
        #pragma unroll
        for (int cc = 0; cc < CPG; ++cc) {
            rL[cc] = vmain ? ls[cc * HW_ + xmain] : 0.0f;
            rR[cc] = vmain ? rs[cc * HW_ + xmain] : 0.0f;
            rF[cc] = rf[cc * HW_ + w];
        }
        if (w < 32) {
            const float* p = (hcs < 4) ? ls : rs;
            hx = hval ? p[(hcs & 3) * HW_ + hx2] : 0.0f;
        }
    };
    auto WRITEROW = [&](int buf) {
        #pragma unroll
        for (int cc = 0; cc < CPG; ++cc) {
            sL[buf][cc][w] = rL[cc];
            sR[buf][cc][w] = rR[cc];
        }
        if (w < 32) {
            if (hcs < 4) sL[buf][hcs][256 + hk] = hx;
            else         sR[buf][hcs & 3][256 + hk] = hx;
        }
    };

    // ---- prologue: stage row 0 ----
    LOADROW(0);
    WRITEROW(0);
    __syncthreads();

    const float wf = (float)w;
    int cur = 0;

    #pragma unroll
    for (int r = 0; r < ROWS; ++r) {
        // snapshot ref (LOADROW below overwrites rF with row r+1)
        v2f fr01, fr23;
        fr01.x = rF[0]; fr01.y = rF[1];
        fr23.x = rF[2]; fr23.y = rF[3];
        const float frq = fr01.x * fr01.x + fr01.y * fr01.y
                        + fr23.x * fr23.x + fr23.y * fr23.y;

        // issue next row's loads; they resolve under this row's compute
        if (r + 1 < ROWS) LOADROW(r + 1);

        // ---- disp-dependent setup (same math as R3) ----
        const float dbase = dsp[r];
        const float s0 = wf + dbase;
        const int i0l = (int)floorf(s0 - 0.4f);
        int relL = i0l - w;
        relL = relL < -1 ? -1 : (relL > 0 ? 0 : relL);
        const float a1l = (s0 - (float)(w + relL)) - 1.0f;

        const float s1 = wf - dbase;
        const int i0r = (int)floorf(s1 - 0.4f);
        int relR = i0r - w;
        relR = relR < -2 ? -2 : (relR > -1 ? -1 : relR);
        const float a1r = (s1 - (float)(w + relR)) - 1.0f;

        const int baseL = w + relL + 2;
        const int baseR = w + relR + 2;

        v2f tl01[3], tl23[3], tr01[3], tr23[3];
        #pragma unroll
        for (int k = 0; k < 3; ++k) {
            tl01[k].x = sL[cur][0][baseL + k];
            tl01[k].y = sL[cur][1][baseL + k];
            tl23[k].x = sL[cur][2][baseL + k];
            tl23[k].y = sL[cur][3][baseL + k];
            tr01[k].x = sR[cur][0][baseR + k];
            tr01[k].y = sR[cur][1][baseR + k];
            tr23[k].x = sR[cur][2][baseR + k];
            tr23[k].y = sR[cur][3][baseR + k];
        }

        const unsigned obase =
            (unsigned)(((b * G_ + g) * D_) * HW_ + (h0 + r) * W_ + w);

        #pragma unroll
        for (int d = 0; d < D_; ++d) {
            const float tlw = a1l + kRes[d];
            const float W0l = fmaxf(-tlw, 0.0f);
            const float W1l = 1.0f - fabsf(tlw);
            const float W2l = fmaxf(tlw, 0.0f);
            const float trw = a1r - kRes[d];
            const float W0r = fmaxf(-trw, 0.0f);
            const float W1r = 1.0f - fabsf(trw);
            const float W2r = fmaxf(trw, 0.0f);

            v2f wl01 = tl01[0] * sp(W0l) + tl01[1] * sp(W1l) + tl01[2] * sp(W2l);
            v2f wl23 = tl23[0] * sp(W0l) + tl23[1] * sp(W1l) + tl23[2] * sp(W2l);
            v2f wr01 = tr01[0] * sp(W0r) + tr01[1] * sp(W1r) + tr01[2] * sp(W2r);
            v2f wr23 = tr23[0] * sp(W0r) + tr23[1] * sp(W1r) + tr23[2] * sp(W2r);

            v2f q   = wl01 * wl01 + wr01 * wr01 + wl23 * wl23 + wr23 * wr23;
            v2f s01 = wl01 + wr01 + fr01;
            v2f s23 = wl23 + wr23 + fr23;
            v2f s2  = s01 * s01 + s23 * s23;

            const float Q  = q.x + q.y + frq;
            const float S2 = s2.x + s2.y;
            const float val = (Q - S2 * (1.0f / 3.0f)) * (1.0f / 12.0f);
            __builtin_nontemporal_store(
                val, &out[obase + (unsigned)d * (unsigned)HW_]);
        }

        // ---- rotate double buffer: write-late for row r+1 ----
        if (r + 1 < ROWS) {
            __syncthreads();          // all waves done reading buf[cur^1]
            WRITEROW(cur ^ 1);        // compiler inserts vmcnt before ds_write
            __syncthreads();          // row r+1 visible
            cur ^= 1;
        }
    }
}

extern "C" void kernel_launch(void* const* d_in, const int* in_sizes, int n_in,
                              void* d_out, int out_size, void* d_ws, size_t ws_size,
                              hipStream_t stream) {
    const float* fref  = (const float*)d_in[0];
    const float* fls   = (const float*)d_in[1];
    const float* frs   = (const float*)d_in[2];
    const float* disp0 = (const float*)d_in[3];
    float* out = (float*)d_out;

    dim3 grid(B_ * G_ * (H_ / ROWS));
    dim3 block(W_);
    cost_volume_kernel<<<grid, block, 0, stream>>>(fref, fls, frs, disp0, out);
}